// Round 20
// baseline (252.207 us; speedup 1.0000x reference)
//
#include <hip/hip_runtime.h>

// ---------------------------------------------------------------------------
// Edge-conditioned kernel MLP, fully fused. R20 = R19 with the compile
// artifact removed (stray b4_dummy dead code).
//   Layers 1/2: R10 verbatim (16x16 MFMA, LDS-staged swizzled W, verified).
//   Layer 3:    NO LDS W, NO barriers. A-frags are global b128 loads from an
//               UNSWIZZLED W3^T workspace (32KB/chunk, L1/L2-resident);
//               B-frags re-read per chunk from sA (h2, never overwritten).
//               Wave (eg=w&3, nh=w>>2) = 32 edges x 64 features, 32x32x16
//               MFMA with the R17/R18-HW-VERIFIED mapping:
//               o = c*4 + 2nh + f, i = q*8 + l5*4 + j; b3-folded gemv,
//               owner half-wave (c>>2==l5) stores float2.
// ---------------------------------------------------------------------------

typedef __bf16 bf16x8 __attribute__((ext_vector_type(8)));
typedef __bf16 bf16x4 __attribute__((ext_vector_type(4)));
typedef float f32x4 __attribute__((ext_vector_type(4)));
typedef float f32x16 __attribute__((ext_vector_type(16)));

#define N_EDGES 147456
#define TM 128            // edges per block = 8 waves x 16 (L1/L2 view)
#define NTHR 512

__device__ __forceinline__ unsigned short f2bf(float f) {
    unsigned u = __float_as_uint(f);
    u = u + 0x7FFFu + ((u >> 16) & 1u);   // RNE (prep kernel only)
    return (unsigned short)(u >> 16);
}
__device__ __forceinline__ float gelu_t(float x) {
    float z = 0.7978845608f * (x + 0.044715f * x * x * x);
    return x / (1.0f + __expf(-2.0f * z));   // tanh-GELU, dev <= ~1e-3
}
__device__ __forceinline__ void gl_lds16(const unsigned short* g, unsigned char* l) {
    __builtin_amdgcn_global_load_lds(
        (const __attribute__((address_space(1))) unsigned int*)g,
        (__attribute__((address_space(3))) unsigned int*)l, 16, 0, 0);
}

// Prep: W1,W2 swizzled (verified R7-R18 verbatim); W3^T UNSWIZZLED [n][k]
// (layer 3 reads it with plain global loads now).
__global__ void prep_weights(const float* __restrict__ W1,
                             const float* __restrict__ W2,
                             const float* __restrict__ W3,
                             unsigned short* __restrict__ ws) {
    int t = blockIdx.x * 256 + threadIdx.x;          // 163840 total
    if (t < 16384) {
        int k = t >> 7, n = t & 127;
        ws[n * 128 + (((k >> 3) ^ (n & 7)) << 3) + (k & 7)] = f2bf(W1[t]);
    } else if (t < 32768) {
        int j = t - 16384;
        int k = j >> 7, n = j & 127;
        ws[16384 + n * 128 + (((k >> 3) ^ (n & 7)) << 3) + (k & 7)] = f2bf(W2[j]);
    } else {
        int j = t - 32768;                           // j = k*1024 + n
        int k = j >> 10, n = j & 1023;
        ws[32768 + n * 128 + k] = f2bf(W3[j]);       // unswizzled [n][k]
    }
}

__global__ __launch_bounds__(NTHR, 4)
void fused_edge_mlp(const float* __restrict__ edge, const float* __restrict__ x,
                    const float* __restrict__ b1, const float* __restrict__ g1,
                    const float* __restrict__ be1,
                    const float* __restrict__ b2, const float* __restrict__ g2,
                    const float* __restrict__ be2,
                    const float* __restrict__ b3,
                    const unsigned short* __restrict__ wsW,
                    float* __restrict__ out) {
    // sA: bf16 [128 rows][128 k], XOR-swizzled. edge->h1->h2; read-only in L3.
    __shared__ __align__(16) unsigned char sA[TM * 256];       // 32 KB
    // sW: bf16 W^T tile [128 n][128 k], swizzled (W1 then W2 only).
    __shared__ __align__(16) unsigned char sW[128 * 256];      // 32 KB

    const int t    = threadIdx.x;
    const int lane = t & 63;
    const int w    = t >> 6;          // 8 waves
    const int e0   = blockIdx.x * TM;
    const int erow = w * 16;          // L1/L2: wave's edge rows
    const int mrow = lane & 15;
    const int hi   = lane >> 4;
    const int eg   = w & 3;           // L3: edge group (32 edges)
    const int nh   = w >> 2;          // L3: feature half (64 of 128)
    const int r31  = lane & 31;
    const int l5   = lane >> 5;
    const int swzl = (lane & 7) << 4; // == (mrow&7)<<4 == (r31&7)<<4
    const f32x4 zz = {0.f, 0.f, 0.f, 0.f};
    const f32x16 zz16 = {0.f,0.f,0.f,0.f,0.f,0.f,0.f,0.f,
                         0.f,0.f,0.f,0.f,0.f,0.f,0.f,0.f};

    // ---- W staging for L1/L2 (R10 verbatim, dst = sW) ----
    auto stageW = [&](const unsigned short* srcW) {
#pragma unroll
        for (int i = 0; i < 4; i++) {
            int base = w * 256 + i * 64;             // 2048 x 16B chunks total
            gl_lds16(srcW + (size_t)(base + lane) * 8, sW + (size_t)base * 16);
        }
    };

    // ---- L1/L2 MFMA (R10 verbatim): C[n=128][e=16] += W(sW)^T . h(sA) ----
    auto runMM = [&](f32x4 (&acc)[8]) {
#pragma unroll
        for (int kk = 0; kk < 4; kk++) {
            int kb = (kk * 64 + hi * 16) ^ swzl;
            bf16x8 bB = *(const bf16x8*)(sA + (erow + mrow) * 256 + kb);
#pragma unroll
            for (int fn = 0; fn < 8; fn++) {
                bf16x8 a = *(const bf16x8*)(sW + (fn * 16 + mrow) * 256 + kb);
                acc[fn] = __builtin_amdgcn_mfma_f32_16x16x32_bf16(
                    a, bB, (kk == 0) ? zz : acc[fn], 0, 0, 0);
            }
        }
    };
    // C/D: col(e-local-16) = mrow, feature n = fn*16 + hi*4 + rr.

    // ---- LN + GELU (R10 verbatim); h -> own sA row ----
    auto lnGelu = [&](f32x4 (&acc)[8], const float* bb, const float* gg,
                      const float* ee) {
        float hv[8][4];
        float s = 0.f, s2 = 0.f;
#pragma unroll
        for (int fn = 0; fn < 8; fn++) {
            f32x4 b4 = *(const f32x4*)(bb + fn * 16 + hi * 4);
#pragma unroll
            for (int rr = 0; rr < 4; rr++) {
                float v = acc[fn][rr] + b4[rr];
                hv[fn][rr] = v; s += v; s2 += v * v;
            }
        }
        s  += __shfl_xor(s, 16);  s  += __shfl_xor(s, 32);
        s2 += __shfl_xor(s2, 16); s2 += __shfl_xor(s2, 32);
        float mean = s * (1.0f / 128.0f);
        float rsv  = rsqrtf(s2 * (1.0f / 128.0f) - mean * mean + 1e-5f);
        int row = erow + mrow;                       // row&7 == lane&7
#pragma unroll
        for (int fn = 0; fn < 8; fn++) {
            f32x4 g4 = *(const f32x4*)(gg + fn * 16 + hi * 4);
            f32x4 e4 = *(const f32x4*)(ee + fn * 16 + hi * 4);
            bf16x4 u;
#pragma unroll
            for (int rr = 0; rr < 4; rr++) {
                float f = (hv[fn][rr] - mean) * rsv * g4[rr] + e4[rr];
                u[rr] = (__bf16)gelu_t(f);           // v_cvt_pk_bf16_f32 (RNE)
            }
            *(bf16x4*)(sA + row * 256 + ((fn * 32 + hi * 8) ^ swzl)) = u;
        }
    };

    // ================= prologue =================
    stageW(wsW);                                     // W1 DMA (overlaps below)
#pragma unroll
    for (int i = 0; i < 4; i++) {                    // edge -> sA (R10 verbatim)
        int c = lane + i * 64;                       // 256 chunks of 8 floats
        int r = erow + (c >> 4), kg = c & 15;
        const float* src = edge + (size_t)(e0 + r) * 128 + kg * 8;
        float4 v0 = *(const float4*)src, v1 = *(const float4*)(src + 4);
        bf16x8 u;
        u[0] = (__bf16)v0.x; u[1] = (__bf16)v0.y; u[2] = (__bf16)v0.z; u[3] = (__bf16)v0.w;
        u[4] = (__bf16)v1.x; u[5] = (__bf16)v1.y; u[6] = (__bf16)v1.z; u[7] = (__bf16)v1.w;
        *(bf16x8*)(sA + r * 256 + ((kg * 16) ^ ((r & 7) << 4))) = u;
    }
    f32x4 xv[4];                      // xv[q][j] = x[e(eg,r31)][q*8 + l5*4 + j]
#pragma unroll
    for (int q = 0; q < 4; q++)
        xv[q] = *(const f32x4*)(
            x + (size_t)(e0 + eg * 32 + r31) * 32 + q * 8 + l5 * 4);
    __syncthreads();                                 // W1 in LDS

    f32x4 acc[8];

    // ================= layer 1 =================
    runMM(acc);                       // reads sW(W1) + own sA row
    __syncthreads();                  // all waves done reading sW(W1)
    stageW(wsW + 16384);              // W2 DMA (overlaps lnGelu VALU)
    lnGelu(acc, b1, g1, be1);         // own sA rows <- h1 (wave-private)
    __syncthreads();                  // W2 ready

    // ================= layer 2 =================
    runMM(acc);                       // reads sW(W2) + own sA row (h1)
    lnGelu(acc, b2, g2, be2);         // own sA rows <- h2 (wave-private)
    __syncthreads();                  // h2 visible block-wide; LAST barrier

    // ================= layer 3: barrier-free, W3 from global =================
    // Wave (eg, nh): C[n = nh*64 + f*32 + r32][e = eg*32 + r31] per chunk c.
    // A: global b128 from unswizzled W3^T. B: sA (h2), R17-verified address.
    const unsigned short* w3t = wsW + 32768;
    f32x16 acc2[2];
#pragma unroll
    for (int c = 0; c < 8; c++) {
#pragma unroll
        for (int ks = 0; ks < 8; ks++) {
            int kb = (ks * 32 + l5 * 16) ^ swzl;
            bf16x8 b = *(const bf16x8*)(sA + (eg * 32 + r31) * 256 + kb);
#pragma unroll
            for (int f = 0; f < 2; f++) {
                bf16x8 a = *(const bf16x8*)(
                    w3t + (size_t)(c * 128 + nh * 64 + f * 32 + r31) * 128
                        + ks * 16 + l5 * 8);
                acc2[f] = __builtin_amdgcn_mfma_f32_32x32x16_bf16(
                    a, b, (ks == 0) ? zz16 : acc2[f], 0, 0, 0);
            }
        }
        // gemv (R17/R18-verified): o = c*4 + 2nh + f, i = q*8 + l5*4 + j
        float pf[2];
#pragma unroll
        for (int f = 0; f < 2; f++) {
            float p = 0.f;
#pragma unroll
            for (int q = 0; q < 4; q++) {
                f32x4 b4 = *(const f32x4*)(
                    b3 + c * 128 + nh * 64 + f * 32 + q * 8 + l5 * 4);
#pragma unroll
                for (int j = 0; j < 4; j++)
                    p += (acc2[f][q * 4 + j] + b4[j]) * xv[q][j];
            }
            p += __shfl_xor(p, 32);                  // other i-half
            pf[f] = p;
        }
        if ((c >> 2) == l5) {                        // owner half-wave stores
            float2 pv = {pf[0], pf[1]};
            *(float2*)(out + (size_t)(e0 + eg * 32 + r31) * 32 + c * 4 + 2 * nh) = pv;
        }
    }
}

extern "C" void kernel_launch(void* const* d_in, const int* in_sizes, int n_in,
                              void* d_out, int out_size, void* d_ws, size_t ws_size,
                              hipStream_t stream) {
    const float* x    = (const float*)d_in[0];
    const float* edge = (const float*)d_in[1];
    const float* W1   = (const float*)d_in[2];
    const float* b1   = (const float*)d_in[3];
    const float* g1   = (const float*)d_in[4];
    const float* be1  = (const float*)d_in[5];
    const float* W2   = (const float*)d_in[6];
    const float* b2   = (const float*)d_in[7];
    const float* g2   = (const float*)d_in[8];
    const float* be2  = (const float*)d_in[9];
    const float* W3   = (const float*)d_in[10];
    const float* b3   = (const float*)d_in[11];
    unsigned short* wsW = (unsigned short*)d_ws;     // W1^T|W2^T swz + W3^T flat
    float* outp = (float*)d_out;

    prep_weights<<<640, 256, 0, stream>>>(W1, W2, W3, wsW);
    fused_edge_mlp<<<N_EDGES / TM, NTHR, 0, stream>>>(
        edge, x, b1, g1, be1, b2, g2, be2, b3, wsW, outp);
}